// Round 2
// baseline (7652.186 us; speedup 1.0000x reference)
//
#include <hip/hip_runtime.h>
#include <hip/hip_bf16.h>
#include <cstdint>
#include <cstddef>

// ---------------- problem constants ----------------
#define BATCH   2
#define SEQLEN  4096
#define DMODEL  2048
#define DINNER  4096
#define NHEADS  64
#define HEADDIM 64
#define DSTATE  64
#define CHUNK   64
#define NCHUNK  (SEQLEN/CHUNK)      // 64
#define DPROJ   8384                // 2*4096 + 2*64 + 64
#define MTOK    (BATCH*SEQLEN)      // 8192
#define RMS_EPS 1e-6f

typedef __hip_bfloat16 bf16;

__device__ __forceinline__ float siluf(float x) { return x / (1.f + expf(-x)); }
__device__ __forceinline__ float to_f(float x) { return x; }
__device__ __forceinline__ float to_f(bf16 x) { return __bfloat162float(x); }
__device__ __forceinline__ void from_f(float& d, float x) { d = x; }
__device__ __forceinline__ void from_f(bf16& d, float x) { d = __float2bfloat16(x); }

// ---------------- tiled GEMM: C[M,N] = A[M,K] @ B[K,N] ----------------
// TA: element type of A (float or bf16); TC: element type of C.
// fp32 math in registers/LDS. BM=128, BN=64, BK=16; 256 threads; 8x4/thread.
template <typename TA, typename TC>
__global__ __launch_bounds__(256) void gemm_tiled(
    const TA* __restrict__ A, int lda,
    const float* __restrict__ B, int ldb,
    TC* __restrict__ C, int ldc, int Kdim) {
  __shared__ float As[16][129];
  __shared__ float Bs[16][65];
  const int tid = threadIdx.x;
  const int tx = tid & 15;    // col group
  const int ty = tid >> 4;    // row group
  const int m0 = blockIdx.y * 128;
  const int n0 = blockIdx.x * 64;
  float acc[8][4];
#pragma unroll
  for (int i = 0; i < 8; ++i)
#pragma unroll
    for (int j = 0; j < 4; ++j) acc[i][j] = 0.f;

  for (int k0 = 0; k0 < Kdim; k0 += 16) {
#pragma unroll
    for (int l = 0; l < 8; ++l) {           // A tile 128x16
      int idx = tid + 256 * l;
      int r = idx >> 4, c = idx & 15;
      As[c][r] = to_f(A[(size_t)(m0 + r) * lda + k0 + c]);
    }
#pragma unroll
    for (int l = 0; l < 4; ++l) {           // B tile 16x64
      int idx = tid + 256 * l;
      int r = idx >> 6, c = idx & 63;
      Bs[r][c] = B[(size_t)(k0 + r) * ldb + n0 + c];
    }
    __syncthreads();
#pragma unroll
    for (int kk = 0; kk < 16; ++kk) {
      float a[8], bb[4];
#pragma unroll
      for (int i = 0; i < 8; ++i) a[i] = As[kk][ty + 16 * i];
#pragma unroll
      for (int j = 0; j < 4; ++j) bb[j] = Bs[kk][tx + 16 * j];
#pragma unroll
      for (int i = 0; i < 8; ++i)
#pragma unroll
        for (int j = 0; j < 4; ++j) acc[i][j] += a[i] * bb[j];
    }
    __syncthreads();
  }
#pragma unroll
  for (int i = 0; i < 8; ++i)
#pragma unroll
    for (int j = 0; j < 4; ++j)
      from_f(C[(size_t)(m0 + ty + 16 * i) * ldc + n0 + tx + 16 * j], acc[i][j]);
}

// ---------------- depthwise causal conv1d (K=4) + SiLU ----------------
// reads x-columns [4096,8192) of zx (bf16), writes xc (bf16, M x 4096)
__global__ __launch_bounds__(256) void conv_silu_kernel(
    const bf16* __restrict__ zx, const float* __restrict__ cw,
    const float* __restrict__ cb, bf16* __restrict__ xc) {
  int idx = blockIdx.x * 256 + threadIdx.x;
  int d = idx & (DINNER - 1);
  int m = idx >> 12;
  int l = m & (SEQLEN - 1);
  int b = m >> 12;
  float acc = cb[d];
#pragma unroll
  for (int k = 0; k < 4; ++k) {
    int li = l - 3 + k;
    if (li >= 0)
      acc += to_f(zx[(size_t)(b * SEQLEN + li) * DPROJ + DINNER + d]) * cw[k * DINNER + d];
  }
  from_f(xc[(size_t)m * DINNER + d], siluf(acc));
}

// ---------------- B/C elu+1, log-decay la (fp32 outputs, small) ----------------
__global__ __launch_bounds__(256) void prep_kernel(
    const bf16* __restrict__ zx, const float* __restrict__ A_log,
    const float* __restrict__ dt_bias, float* __restrict__ Bm,
    float* __restrict__ Cm, float* __restrict__ la) {
  int idx = blockIdx.x * 256 + threadIdx.x;  // m*64 + j
  int j = idx & 63;
  int m = idx >> 6;
  const bf16* row = zx + (size_t)m * DPROJ;
  float bv = to_f(row[2 * DINNER + j]);
  float cv = to_f(row[2 * DINNER + DSTATE + j]);
  float dtl = to_f(row[2 * DINNER + 2 * DSTATE + j]) + dt_bias[j];
  Bm[idx] = bv > 0.f ? bv + 1.f : expf(bv);
  Cm[idx] = cv > 0.f ? cv + 1.f : expf(cv);
  float dt = dtl > 20.f ? dtl : log1pf(expf(dtl));
  la[idx] = -dt * expf(A_log[j]);   // log(a)
}

// ---------------- per-chunk inclusive cumsum of log-decay ----------------
__global__ __launch_bounds__(64) void cumsum_kernel(
    const float* __restrict__ la, float* __restrict__ cs) {
  int bid = blockIdx.x;           // b*4096 + h*64 + c
  int c = bid & 63, h = (bid >> 6) & 63, b = bid >> 12;
  int s = threadIdx.x;
  __shared__ float lds[64];
  size_t base = (size_t)(b * SEQLEN + c * CHUNK + s) * 64 + h;
  lds[s] = la[base];
  __syncthreads();
  float acc = 0.f;
  for (int t = 0; t <= s; ++t) acc += lds[t];
  cs[base] = acc;
}

// ---------------- per-chunk state: st[n][p] = sum_s k_scaled[s][n]*v[s][p] ----------------
__global__ __launch_bounds__(256) void states_kernel(
    const float* __restrict__ Bm, const bf16* __restrict__ xc,
    const float* __restrict__ cs, bf16* __restrict__ st) {
  int bid = blockIdx.x;           // b*4096 + h*64 + c
  int c = bid & 63, h = (bid >> 6) & 63, b = bid >> 12;
  int m0 = b * SEQLEN + c * CHUNK;
  __shared__ float ks[64][65];
  int tid = threadIdx.x;
  float cstot = cs[(size_t)(m0 + 63) * 64 + h];
#pragma unroll
  for (int i = 0; i < 16; ++i) {
    int idx = tid + 256 * i;
    int s = idx >> 6, n = idx & 63;
    float w = expf(cstot - cs[(size_t)(m0 + s) * 64 + h]);
    ks[s][n] = Bm[(size_t)(m0 + s) * 64 + n] * w;
  }
  __syncthreads();
  int p = tid & 63, g = tid >> 6;   // g in 0..3
  float acc[16];
#pragma unroll
  for (int i = 0; i < 16; ++i) acc[i] = 0.f;
  for (int s = 0; s < 64; ++s) {
    float v = to_f(xc[(size_t)(m0 + s) * DINNER + h * HEADDIM + p]);
#pragma unroll
    for (int i = 0; i < 16; ++i) acc[i] += ks[s][g * 16 + i] * v;
  }
  size_t ob = ((size_t)(b * NHEADS + h) * NCHUNK + c) * 4096;
#pragma unroll
  for (int i = 0; i < 16; ++i) from_f(st[ob + (size_t)(g * 16 + i) * 64 + p], acc[i]);
}

// ---------------- sequential scan over chunks (in place: st becomes h_prev) ----------------
__global__ __launch_bounds__(256) void scan_kernel(
    const float* __restrict__ cs, bf16* __restrict__ st) {
  int bh = blockIdx.x;            // b*64 + h
  int b = bh >> 6, h = bh & 63;
  int tid = threadIdx.x;
  float hreg[16];
#pragma unroll
  for (int i = 0; i < 16; ++i) hreg[i] = 0.f;
  size_t base = (size_t)bh * NCHUNK * 4096;
  for (int c = 0; c < NCHUNK; ++c) {
    float d = expf(cs[(size_t)(b * SEQLEN + c * CHUNK + 63) * 64 + h]);
    size_t cb = base + (size_t)c * 4096;
#pragma unroll
    for (int i = 0; i < 16; ++i) {
      size_t e = cb + tid + 256 * i;
      float sv = to_f(st[e]);
      from_f(st[e], hreg[i]);          // emit state at chunk start
      hreg[i] = d * hreg[i] + sv;
    }
  }
}

// ---------------- per-chunk output: y = att@v + (q*e^cs)@h_prev + D*v ----------------
// writes y (bf16) into the (now free) x-region of zx
__global__ __launch_bounds__(256) void chunk_out_kernel(
    const float* __restrict__ Bm, const float* __restrict__ Cm,
    const bf16* __restrict__ xc, const float* __restrict__ cs,
    const bf16* __restrict__ st, const float* __restrict__ Dp,
    bf16* __restrict__ zx) {
  int bid = blockIdx.x;           // b*4096 + h*64 + c
  int c = bid & 63, h = (bid >> 6) & 63, b = bid >> 12;
  int m0 = b * SEQLEN + c * CHUNK;
  int tid = threadIdx.x;
  __shared__ float qs[64][65];
  __shared__ float kh[64][65];    // k in phase 1, h_prev in phase 2
  __shared__ float vs[64][65];
  __shared__ float att[64][65];
  __shared__ float csl[64];
#pragma unroll
  for (int i = 0; i < 16; ++i) {
    int idx = tid + 256 * i;
    int s = idx >> 6, n = idx & 63;
    qs[s][n] = Cm[(size_t)(m0 + s) * 64 + n];
    kh[s][n] = Bm[(size_t)(m0 + s) * 64 + n];
    vs[s][n] = to_f(xc[(size_t)(m0 + s) * DINNER + h * HEADDIM + n]);
  }
  if (tid < 64) csl[tid] = cs[(size_t)(m0 + tid) * 64 + h];
  __syncthreads();
  // phase 1: att[s][t] = (q_s . k_t) * exp(cs_s - cs_t), causal
#pragma unroll
  for (int i = 0; i < 16; ++i) {
    int idx = tid + 256 * i;
    int s = idx >> 6, t = idx & 63;
    float val = 0.f;
    if (t <= s) {
      float dot = 0.f;
#pragma unroll
      for (int n = 0; n < 64; ++n) dot += qs[s][n] * kh[t][n];
      val = dot * expf(csl[s] - csl[t]);
    }
    att[s][t] = val;
  }
  __syncthreads();
  // load h_prev into kh
  size_t hb = ((size_t)(b * NHEADS + h) * NCHUNK + c) * 4096;
#pragma unroll
  for (int i = 0; i < 16; ++i) {
    int idx = tid + 256 * i;
    kh[idx >> 6][idx & 63] = to_f(st[hb + idx]);
  }
  __syncthreads();
  float Dh = Dp[h];
#pragma unroll
  for (int i = 0; i < 16; ++i) {
    int idx = tid + 256 * i;
    int s = idx >> 6, p = idx & 63;
    float acc = Dh * vs[s][p];
    for (int t = 0; t <= s; ++t) acc += att[s][t] * vs[t][p];
    float es = expf(csl[s]);
#pragma unroll
    for (int n = 0; n < 64; ++n) acc += qs[s][n] * es * kh[n][p];
    from_f(zx[(size_t)(m0 + s) * DPROJ + DINNER + h * HEADDIM + p], acc);
  }
}

// ---------------- RMSNorm over 4096 + silu(z) gate, in place on y region ----------------
__global__ __launch_bounds__(256) void rmsnorm_gate_kernel(
    bf16* __restrict__ zx, const float* __restrict__ scale) {
  int m = blockIdx.x;
  int tid = threadIdx.x;
  bf16* row = zx + (size_t)m * DPROJ;   // z at [0,4096), y at [4096,8192)
  float vals[16];
  float ss = 0.f;
#pragma unroll
  for (int i = 0; i < 16; ++i) {
    int d = tid + 256 * i;
    float y = to_f(row[DINNER + d]);
    vals[i] = y;
    ss += y * y;
  }
#pragma unroll
  for (int off = 32; off > 0; off >>= 1) ss += __shfl_down(ss, off, 64);
  __shared__ float red[4];
  if ((tid & 63) == 0) red[tid >> 6] = ss;
  __syncthreads();
  float tot = red[0] + red[1] + red[2] + red[3];
  float inv = rsqrtf(tot / (float)DINNER + RMS_EPS);
#pragma unroll
  for (int i = 0; i < 16; ++i) {
    int d = tid + 256 * i;
    float z = to_f(row[d]);
    from_f(row[DINNER + d], vals[i] * inv * scale[d] * siluf(z));
  }
}

// ---------------- launch ----------------
extern "C" void kernel_launch(void* const* d_in, const int* in_sizes, int n_in,
                              void* d_out, int out_size, void* d_ws, size_t ws_size,
                              hipStream_t stream) {
  const float* u       = (const float*)d_in[0];
  const float* Win     = (const float*)d_in[1];
  const float* cw      = (const float*)d_in[2];
  const float* cb      = (const float*)d_in[3];
  const float* A_log   = (const float*)d_in[4];
  const float* dt_bias = (const float*)d_in[5];
  const float* Dp      = (const float*)d_in[6];
  const float* nscale  = (const float*)d_in[7];
  const float* Wout    = (const float*)d_in[8];
  float* out = (float*)d_out;

  // workspace layout: bf16 big buffers + small fp32 arrays, ~213 MB total.
  // st (chunk states, bf16, 64 MiB) lives in d_out — exactly out_size*4 bytes,
  // dead until the final GEMM overwrites it.
  bf16* zx = (bf16*)d_ws;                        // MTOK*DPROJ bf16 (z|x|B|C|dt; x-region reused for y)
  bf16* xc = zx + (size_t)MTOK * DPROJ;          // MTOK*DINNER bf16 (conv+silu output = v)
  float* Bm = (float*)(xc + (size_t)MTOK * DINNER);  // MTOK*64 f32
  float* Cm = Bm + (size_t)MTOK * 64;
  float* la = Cm + (size_t)MTOK * 64;
  float* cs = la + (size_t)MTOK * 64;
  bf16* st = (bf16*)d_out;                       // B*H*C*64*64 bf16 == 64 MiB

  // 1) in-projection GEMM: zx = u @ Win   (8192 x 8384, K=2048)
  gemm_tiled<float, bf16><<<dim3(DPROJ / 64, MTOK / 128), 256, 0, stream>>>(u, DMODEL, Win, DPROJ, zx, DPROJ, DMODEL);
  // 2) causal depthwise conv + SiLU -> xc
  conv_silu_kernel<<<(MTOK * DINNER) / 256, 256, 0, stream>>>(zx, cw, cb, xc);
  // 3) B/C elu+1, log-decay
  prep_kernel<<<(MTOK * 64) / 256, 256, 0, stream>>>(zx, A_log, dt_bias, Bm, Cm, la);
  // 4) per-chunk cumsum of log-decay
  cumsum_kernel<<<BATCH * NHEADS * NCHUNK, 64, 0, stream>>>(la, cs);
  // 5) per-chunk states
  states_kernel<<<BATCH * NHEADS * NCHUNK, 256, 0, stream>>>(Bm, xc, cs, st);
  // 6) inter-chunk scan (st becomes h_prev, in place)
  scan_kernel<<<BATCH * NHEADS, 256, 0, stream>>>(cs, st);
  // 7) per-chunk output (intra + inter + skip) -> y into zx x-region
  chunk_out_kernel<<<BATCH * NHEADS * NCHUNK, 256, 0, stream>>>(Bm, Cm, xc, cs, st, Dp, zx);
  // 8) RMSNorm + silu(z) gate, in place
  rmsnorm_gate_kernel<<<MTOK, 256, 0, stream>>>(zx, nscale);
  // 9) out-projection GEMM: out = y_gated @ Wout  (8192 x 2048, K=4096)
  gemm_tiled<bf16, float><<<dim3(DMODEL / 64, MTOK / 128), 256, 0, stream>>>(zx + DINNER, DPROJ, Wout, DMODEL, out, DMODEL, DINNER);
}

// Round 3
// 1668.531 us; speedup vs baseline: 4.5862x; 4.5862x over previous
//
#include <hip/hip_runtime.h>
#include <hip/hip_bf16.h>
#include <cstdint>
#include <cstddef>

// ---------------- problem constants ----------------
#define BATCH   2
#define SEQLEN  4096
#define DMODEL  2048
#define DINNER  4096
#define NHEADS  64
#define HEADDIM 64
#define DSTATE  64
#define CHUNK   64
#define NCHUNK  (SEQLEN/CHUNK)      // 64
#define DPROJ   8384                // 2*4096 + 2*64 + 64
#define DPROJ_PAD 8448              // next multiple of 128
#define MTOK    (BATCH*SEQLEN)      // 8192
#define RMS_EPS 1e-6f

typedef __hip_bfloat16 bf16;
typedef __attribute__((ext_vector_type(8))) short bf16x8;
typedef __attribute__((ext_vector_type(4))) float f32x4;

__device__ __forceinline__ float siluf(float x) { return x / (1.f + expf(-x)); }
__device__ __forceinline__ float to_f(float x) { return x; }
__device__ __forceinline__ float to_f(bf16 x) { return __bfloat162float(x); }
__device__ __forceinline__ void from_f(float& d, float x) { d = x; }
__device__ __forceinline__ void from_f(bf16& d, float x) { d = __float2bfloat16(x); }

// async global->LDS, 16B per lane; LDS dest is wave-uniform base + lane*16
__device__ __forceinline__ void gload16(const void* g, void* l) {
  __builtin_amdgcn_global_load_lds(
      (const __attribute__((address_space(1))) void*)g,
      (__attribute__((address_space(3))) void*)l, 16, 0, 0);
}

// ---------------- MFMA bf16 GEMM: C[M,N] = A[M,K] @ BT[N,K]^T ----------------
// 128x128 tile, BK=32, 4 waves (each 64x64 = 4x4 frags of 16x16x32).
// XOR swizzle: k-slot (16B units) ^= (row&3), applied on pre-swizzled global
// source (global_load_lds dest stays linear) and on the ds_read side.
template <typename TC, bool MASK>
__global__ __launch_bounds__(256) void gemm_mfma(
    const bf16* __restrict__ A, int lda,
    const bf16* __restrict__ BT, int ldb,
    TC* __restrict__ C, int ldc, int Kdim, int Nvalid) {
  __shared__ __align__(16) bf16 As[128 * 32];
  __shared__ __align__(16) bf16 Bs[128 * 32];
  const int tid  = threadIdx.x;
  const int lane = tid & 63;
  const int w    = tid >> 6;
  const int m0 = blockIdx.y * 128;
  const int n0 = blockIdx.x * 128;

  // staging geometry: inst i in {0,1}: LDS rows w*32+i*16 .. +16, linear.
  const int rs0 = w * 32 + (lane >> 2);          // row for inst 0 (inst 1: +16)
  const int ce  = 8 * ((lane & 3) ^ ((lane >> 2) & 3));  // swizzled k-elem offset (row&3 == (lane>>2)&3)
  // ds_read side: lane reads row r=(frag*16 + (lane&15)), k-slot (lane>>4)^(r&3); r&3 == lane&3
  const int fo  = 8 * ((lane >> 4) ^ (lane & 3));
  const int lr  = lane & 15, lg = lane >> 4;
  const int wr = w >> 1, wc = w & 1;

  f32x4 acc[4][4];
#pragma unroll
  for (int m = 0; m < 4; ++m)
#pragma unroll
    for (int n = 0; n < 4; ++n) acc[m][n] = (f32x4){0.f, 0.f, 0.f, 0.f};

  const size_t arow0 = (size_t)(m0 + rs0) * lda;
  const size_t arow1 = (size_t)(m0 + rs0 + 16) * lda;
  const size_t brow0 = (size_t)(n0 + rs0) * ldb;
  const size_t brow1 = (size_t)(n0 + rs0 + 16) * ldb;
  bf16* lA0 = &As[(w * 2 + 0) * 512];
  bf16* lA1 = &As[(w * 2 + 1) * 512];
  bf16* lB0 = &Bs[(w * 2 + 0) * 512];
  bf16* lB1 = &Bs[(w * 2 + 1) * 512];

  for (int k0 = 0; k0 < Kdim; k0 += 32) {
    __syncthreads();   // prior ds_reads done before overwrite
    gload16(A + arow0 + k0 + ce, lA0);
    gload16(A + arow1 + k0 + ce, lA1);
    gload16(BT + brow0 + k0 + ce, lB0);
    gload16(BT + brow1 + k0 + ce, lB1);
    __syncthreads();   // vmcnt(0) drain before barrier -> tiles ready
    bf16x8 af[4], bfr[4];
#pragma unroll
    for (int m = 0; m < 4; ++m)
      af[m] = *(const bf16x8*)&As[(wr * 64 + m * 16 + lr) * 32 + fo];
#pragma unroll
    for (int n = 0; n < 4; ++n)
      bfr[n] = *(const bf16x8*)&Bs[(wc * 64 + n * 16 + lr) * 32 + fo];
#pragma unroll
    for (int m = 0; m < 4; ++m)
#pragma unroll
      for (int n = 0; n < 4; ++n)
        acc[m][n] = __builtin_amdgcn_mfma_f32_16x16x32_bf16(af[m], bfr[n], acc[m][n], 0, 0, 0);
  }

  // epilogue: C/D layout col=lane&15, row=(lane>>4)*4+reg  [m89]
#pragma unroll
  for (int m = 0; m < 4; ++m)
#pragma unroll
    for (int n = 0; n < 4; ++n) {
      int col = n0 + wc * 64 + n * 16 + lr;
      if (MASK && col >= Nvalid) continue;
      size_t rbase = (size_t)(m0 + wr * 64 + m * 16 + lg * 4);
#pragma unroll
      for (int reg = 0; reg < 4; ++reg)
        from_f(C[(rbase + reg) * ldc + col], acc[m][n][reg]);
    }
}

// ---------------- cast fp32 -> bf16 (4/thread) ----------------
__global__ __launch_bounds__(256) void cast_bf16_kernel(
    const float* __restrict__ x, bf16* __restrict__ y) {
  size_t i = ((size_t)blockIdx.x * 256 + threadIdx.x) * 4;
  float4 v = *(const float4*)(x + i);
  y[i + 0] = __float2bfloat16(v.x);
  y[i + 1] = __float2bfloat16(v.y);
  y[i + 2] = __float2bfloat16(v.z);
  y[i + 3] = __float2bfloat16(v.w);
}

// ---------------- transpose + cast: WT[Npad][K] = W[K][N]^T ----------------
__global__ __launch_bounds__(256) void transpose_cast_kernel(
    const float* __restrict__ W, bf16* __restrict__ WT, int N, int K) {
  __shared__ float t[32][33];
  int n0 = blockIdx.x * 32, k0 = blockIdx.y * 32;
  int tx = threadIdx.x & 31, ty = threadIdx.x >> 5;   // ty 0..7
#pragma unroll
  for (int i = 0; i < 4; ++i) {
    int n = n0 + tx;
    t[ty + i * 8][tx] = (n < N) ? W[(size_t)(k0 + ty + i * 8) * N + n] : 0.f;
  }
  __syncthreads();
#pragma unroll
  for (int i = 0; i < 4; ++i) {
    int nn = ty + i * 8;
    WT[(size_t)(n0 + nn) * K + k0 + tx] = __float2bfloat16(t[tx][nn]);
  }
}

// ---------------- depthwise causal conv1d (K=4) + SiLU ----------------
__global__ __launch_bounds__(256) void conv_silu_kernel(
    const bf16* __restrict__ zx, const float* __restrict__ cw,
    const float* __restrict__ cb, bf16* __restrict__ xc) {
  int idx = blockIdx.x * 256 + threadIdx.x;
  int d = idx & (DINNER - 1);
  int m = idx >> 12;
  int l = m & (SEQLEN - 1);
  int b = m >> 12;
  float acc = cb[d];
#pragma unroll
  for (int k = 0; k < 4; ++k) {
    int li = l - 3 + k;
    if (li >= 0)
      acc += to_f(zx[(size_t)(b * SEQLEN + li) * DPROJ + DINNER + d]) * cw[k * DINNER + d];
  }
  from_f(xc[(size_t)m * DINNER + d], siluf(acc));
}

// ---------------- B/C elu+1, log-decay la ----------------
__global__ __launch_bounds__(256) void prep_kernel(
    const bf16* __restrict__ zx, const float* __restrict__ A_log,
    const float* __restrict__ dt_bias, float* __restrict__ Bm,
    float* __restrict__ Cm, float* __restrict__ la) {
  int idx = blockIdx.x * 256 + threadIdx.x;  // m*64 + j
  int j = idx & 63;
  int m = idx >> 6;
  const bf16* row = zx + (size_t)m * DPROJ;
  float bv = to_f(row[2 * DINNER + j]);
  float cv = to_f(row[2 * DINNER + DSTATE + j]);
  float dtl = to_f(row[2 * DINNER + 2 * DSTATE + j]) + dt_bias[j];
  Bm[idx] = bv > 0.f ? bv + 1.f : expf(bv);
  Cm[idx] = cv > 0.f ? cv + 1.f : expf(cv);
  float dt = dtl > 20.f ? dtl : log1pf(expf(dtl));
  la[idx] = -dt * expf(A_log[j]);   // log(a)
}

// ---------------- per-chunk inclusive cumsum of log-decay ----------------
__global__ __launch_bounds__(64) void cumsum_kernel(
    const float* __restrict__ la, float* __restrict__ cs) {
  int bid = blockIdx.x;           // b*4096 + h*64 + c
  int c = bid & 63, h = (bid >> 6) & 63, b = bid >> 12;
  int s = threadIdx.x;
  __shared__ float lds[64];
  size_t base = (size_t)(b * SEQLEN + c * CHUNK + s) * 64 + h;
  lds[s] = la[base];
  __syncthreads();
  float acc = 0.f;
  for (int t = 0; t <= s; ++t) acc += lds[t];
  cs[base] = acc;
}

// ---------------- per-chunk state: st[n][p] = sum_s k_scaled[s][n]*v[s][p] ----------------
__global__ __launch_bounds__(256) void states_kernel(
    const float* __restrict__ Bm, const bf16* __restrict__ xc,
    const float* __restrict__ cs, bf16* __restrict__ st) {
  int bid = blockIdx.x;           // b*4096 + h*64 + c
  int c = bid & 63, h = (bid >> 6) & 63, b = bid >> 12;
  int m0 = b * SEQLEN + c * CHUNK;
  __shared__ float ks[64][65];
  int tid = threadIdx.x;
  float cstot = cs[(size_t)(m0 + 63) * 64 + h];
#pragma unroll
  for (int i = 0; i < 16; ++i) {
    int idx = tid + 256 * i;
    int s = idx >> 6, n = idx & 63;
    float w = expf(cstot - cs[(size_t)(m0 + s) * 64 + h]);
    ks[s][n] = Bm[(size_t)(m0 + s) * 64 + n] * w;
  }
  __syncthreads();
  int p = tid & 63, g = tid >> 6;   // g in 0..3
  float acc[16];
#pragma unroll
  for (int i = 0; i < 16; ++i) acc[i] = 0.f;
  for (int s = 0; s < 64; ++s) {
    float v = to_f(xc[(size_t)(m0 + s) * DINNER + h * HEADDIM + p]);
#pragma unroll
    for (int i = 0; i < 16; ++i) acc[i] += ks[s][g * 16 + i] * v;
  }
  size_t ob = ((size_t)(b * NHEADS + h) * NCHUNK + c) * 4096;
#pragma unroll
  for (int i = 0; i < 16; ++i) from_f(st[ob + (size_t)(g * 16 + i) * 64 + p], acc[i]);
}

// ---------------- sequential scan over chunks (in place: st becomes h_prev) ----------------
__global__ __launch_bounds__(256) void scan_kernel(
    const float* __restrict__ cs, bf16* __restrict__ st) {
  int bh = blockIdx.x;            // b*64 + h
  int b = bh >> 6, h = bh & 63;
  int tid = threadIdx.x;
  float hreg[16];
#pragma unroll
  for (int i = 0; i < 16; ++i) hreg[i] = 0.f;
  size_t base = (size_t)bh * NCHUNK * 4096;
  for (int c = 0; c < NCHUNK; ++c) {
    float d = expf(cs[(size_t)(b * SEQLEN + c * CHUNK + 63) * 64 + h]);
    size_t cb = base + (size_t)c * 4096;
#pragma unroll
    for (int i = 0; i < 16; ++i) {
      size_t e = cb + tid + 256 * i;
      float sv = to_f(st[e]);
      from_f(st[e], hreg[i]);          // emit state at chunk start
      hreg[i] = d * hreg[i] + sv;
    }
  }
}

// ---------------- per-chunk output: y = att@v + (q*e^cs)@h_prev + D*v ----------------
__global__ __launch_bounds__(256) void chunk_out_kernel(
    const float* __restrict__ Bm, const float* __restrict__ Cm,
    const bf16* __restrict__ xc, const float* __restrict__ cs,
    const bf16* __restrict__ st, const float* __restrict__ Dp,
    bf16* __restrict__ zx) {
  int bid = blockIdx.x;           // b*4096 + h*64 + c
  int c = bid & 63, h = (bid >> 6) & 63, b = bid >> 12;
  int m0 = b * SEQLEN + c * CHUNK;
  int tid = threadIdx.x;
  __shared__ float qs[64][65];
  __shared__ float kh[64][65];    // k in phase 1, h_prev in phase 2
  __shared__ float vs[64][65];
  __shared__ float att[64][65];
  __shared__ float csl[64];
#pragma unroll
  for (int i = 0; i < 16; ++i) {
    int idx = tid + 256 * i;
    int s = idx >> 6, n = idx & 63;
    qs[s][n] = Cm[(size_t)(m0 + s) * 64 + n];
    kh[s][n] = Bm[(size_t)(m0 + s) * 64 + n];
    vs[s][n] = to_f(xc[(size_t)(m0 + s) * DINNER + h * HEADDIM + n]);
  }
  if (tid < 64) csl[tid] = cs[(size_t)(m0 + tid) * 64 + h];
  __syncthreads();
#pragma unroll
  for (int i = 0; i < 16; ++i) {
    int idx = tid + 256 * i;
    int s = idx >> 6, t = idx & 63;
    float val = 0.f;
    if (t <= s) {
      float dot = 0.f;
#pragma unroll
      for (int n = 0; n < 64; ++n) dot += qs[s][n] * kh[t][n];
      val = dot * expf(csl[s] - csl[t]);
    }
    att[s][t] = val;
  }
  __syncthreads();
  size_t hb = ((size_t)(b * NHEADS + h) * NCHUNK + c) * 4096;
#pragma unroll
  for (int i = 0; i < 16; ++i) {
    int idx = tid + 256 * i;
    kh[idx >> 6][idx & 63] = to_f(st[hb + idx]);
  }
  __syncthreads();
  float Dh = Dp[h];
#pragma unroll
  for (int i = 0; i < 16; ++i) {
    int idx = tid + 256 * i;
    int s = idx >> 6, p = idx & 63;
    float acc = Dh * vs[s][p];
    for (int t = 0; t <= s; ++t) acc += att[s][t] * vs[t][p];
    float es = expf(csl[s]);
#pragma unroll
    for (int n = 0; n < 64; ++n) acc += qs[s][n] * es * kh[n][p];
    from_f(zx[(size_t)(m0 + s) * DPROJ + DINNER + h * HEADDIM + p], acc);
  }
}

// ---------------- RMSNorm over 4096 + silu(z) gate ----------------
__global__ __launch_bounds__(256) void rmsnorm_gate_kernel(
    bf16* __restrict__ zx, const float* __restrict__ scale) {
  int m = blockIdx.x;
  int tid = threadIdx.x;
  bf16* row = zx + (size_t)m * DPROJ;   // z at [0,4096), y at [4096,8192)
  float vals[16];
  float ss = 0.f;
#pragma unroll
  for (int i = 0; i < 16; ++i) {
    int d = tid + 256 * i;
    float y = to_f(row[DINNER + d]);
    vals[i] = y;
    ss += y * y;
  }
#pragma unroll
  for (int off = 32; off > 0; off >>= 1) ss += __shfl_down(ss, off, 64);
  __shared__ float red[4];
  if ((tid & 63) == 0) red[tid >> 6] = ss;
  __syncthreads();
  float tot = red[0] + red[1] + red[2] + red[3];
  float inv = rsqrtf(tot / (float)DINNER + RMS_EPS);
#pragma unroll
  for (int i = 0; i < 16; ++i) {
    int d = tid + 256 * i;
    float z = to_f(row[d]);
    from_f(row[DINNER + d], vals[i] * inv * scale[d] * siluf(z));
  }
}

// ---------------- launch ----------------
extern "C" void kernel_launch(void* const* d_in, const int* in_sizes, int n_in,
                              void* d_out, int out_size, void* d_ws, size_t ws_size,
                              hipStream_t stream) {
  const float* u       = (const float*)d_in[0];
  const float* Win     = (const float*)d_in[1];
  const float* cw      = (const float*)d_in[2];
  const float* cb      = (const float*)d_in[3];
  const float* A_log   = (const float*)d_in[4];
  const float* dt_bias = (const float*)d_in[5];
  const float* Dp      = (const float*)d_in[6];
  const float* nscale  = (const float*)d_in[7];
  const float* Wout    = (const float*)d_in[8];
  float* out = (float*)d_out;

  // workspace (~248 MB):
  //   zx  : MTOK*DPROJ bf16                    137.4 MB
  //   xc  : MTOK*DINNER bf16 (ub overlays it)   67.1 MB
  //   wT  : DPROJ_PAD*DMODEL bf16 (WinT, then WoutT)  34.6 MB
  //   Bm/Cm/la/cs : MTOK*64 f32 each             8.4 MB
  bf16* zx = (bf16*)d_ws;
  bf16* xc = zx + (size_t)MTOK * DPROJ;
  bf16* ub = xc;                                  // overlay: ub dead before xc written
  bf16* wT = xc + (size_t)MTOK * DINNER;
  float* Bm = (float*)(wT + (size_t)DPROJ_PAD * DMODEL);
  float* Cm = Bm + (size_t)MTOK * 64;
  float* la = Cm + (size_t)MTOK * 64;
  float* cs = la + (size_t)MTOK * 64;
  bf16* st = (bf16*)d_out;                        // chunk states, 64 MiB, dead before GEMM2

  // 0a) u -> bf16
  cast_bf16_kernel<<<(MTOK * DMODEL) / (256 * 4), 256, 0, stream>>>(u, ub);
  // 0b) Win^T (padded to 8448 rows) -> bf16
  transpose_cast_kernel<<<dim3(DPROJ_PAD / 32, DMODEL / 32), 256, 0, stream>>>(Win, wT, DPROJ, DMODEL);
  // 1) in-projection: zx = ub @ WinT^T   (M=8192, N=8384(pad 8448), K=2048)
  gemm_mfma<bf16, true><<<dim3(DPROJ_PAD / 128, MTOK / 128), 256, 0, stream>>>(
      ub, DMODEL, wT, DMODEL, zx, DPROJ, DMODEL, DPROJ);
  // 0c) Wout^T -> bf16 (reuses wT; WinT dead)
  transpose_cast_kernel<<<dim3(DMODEL / 32, DINNER / 32), 256, 0, stream>>>(Wout, wT, DMODEL, DINNER);
  // 2) causal depthwise conv + SiLU -> xc
  conv_silu_kernel<<<(MTOK * DINNER) / 256, 256, 0, stream>>>(zx, cw, cb, xc);
  // 3) B/C elu+1, log-decay
  prep_kernel<<<(MTOK * 64) / 256, 256, 0, stream>>>(zx, A_log, dt_bias, Bm, Cm, la);
  // 4) per-chunk cumsum
  cumsum_kernel<<<BATCH * NHEADS * NCHUNK, 64, 0, stream>>>(la, cs);
  // 5) per-chunk states
  states_kernel<<<BATCH * NHEADS * NCHUNK, 256, 0, stream>>>(Bm, xc, cs, st);
  // 6) inter-chunk scan
  scan_kernel<<<BATCH * NHEADS, 256, 0, stream>>>(cs, st);
  // 7) per-chunk output -> y into zx x-region
  chunk_out_kernel<<<BATCH * NHEADS * NCHUNK, 256, 0, stream>>>(Bm, Cm, xc, cs, st, Dp, zx);
  // 8) RMSNorm + silu(z) gate
  rmsnorm_gate_kernel<<<MTOK, 256, 0, stream>>>(zx, nscale);
  // 9) out-projection: out = y @ WoutT^T  (M=8192, N=2048, K=4096)
  gemm_mfma<float, false><<<dim3(DMODEL / 128, MTOK / 128), 256, 0, stream>>>(
      zx + DINNER, DPROJ, wT, DINNER, out, DMODEL, DINNER, DMODEL);
}

// Round 4
// 911.703 us; speedup vs baseline: 8.3933x; 1.8301x over previous
//
#include <hip/hip_runtime.h>
#include <hip/hip_bf16.h>
#include <cstdint>
#include <cstddef>

// ---------------- problem constants ----------------
#define BATCH   2
#define SEQLEN  4096
#define DMODEL  2048
#define DINNER  4096
#define NHEADS  64
#define HEADDIM 64
#define DSTATE  64
#define CHUNK   64
#define NCHUNK  (SEQLEN/CHUNK)      // 64
#define DPROJ   8384                // 2*4096 + 2*64 + 64
#define DPROJ_PAD 8448              // next multiple of 128
#define MTOK    (BATCH*SEQLEN)      // 8192
#define RMS_EPS 1e-6f

typedef __hip_bfloat16 bf16;
typedef __attribute__((ext_vector_type(8))) short bf16x8;
typedef __attribute__((ext_vector_type(4))) float f32x4;

__device__ __forceinline__ float siluf(float x) { return x / (1.f + expf(-x)); }
__device__ __forceinline__ float to_f(float x) { return x; }
__device__ __forceinline__ float to_f(bf16 x) { return __bfloat162float(x); }
__device__ __forceinline__ void from_f(float& d, float x) { d = x; }
__device__ __forceinline__ void from_f(bf16& d, float x) { d = __float2bfloat16(x); }

// async global->LDS, 16B per lane; LDS dest is wave-uniform base + lane*16
__device__ __forceinline__ void gload16(const void* g, void* l) {
  __builtin_amdgcn_global_load_lds(
      (const __attribute__((address_space(1))) void*)g,
      (__attribute__((address_space(3))) void*)l, 16, 0, 0);
}

// ---------------- MFMA bf16 GEMM: C[M,N] = A[M,K] @ BT[N,K]^T ----------------
// 128x128 tile, BK=32, 4 waves. XOR swizzle on global source + ds_read side.
template <typename TC, bool MASK>
__global__ __launch_bounds__(256) void gemm_mfma(
    const bf16* __restrict__ A, int lda,
    const bf16* __restrict__ BT, int ldb,
    TC* __restrict__ C, int ldc, int Kdim, int Nvalid) {
  __shared__ __align__(16) bf16 As[128 * 32];
  __shared__ __align__(16) bf16 Bs[128 * 32];
  const int tid  = threadIdx.x;
  const int lane = tid & 63;
  const int w    = tid >> 6;
  const int m0 = blockIdx.y * 128;
  const int n0 = blockIdx.x * 128;

  const int rs0 = w * 32 + (lane >> 2);
  const int ce  = 8 * ((lane & 3) ^ ((lane >> 2) & 3));
  const int fo  = 8 * ((lane >> 4) ^ (lane & 3));
  const int lr  = lane & 15, lg = lane >> 4;
  const int wr = w >> 1, wc = w & 1;

  f32x4 acc[4][4];
#pragma unroll
  for (int m = 0; m < 4; ++m)
#pragma unroll
    for (int n = 0; n < 4; ++n) acc[m][n] = (f32x4){0.f, 0.f, 0.f, 0.f};

  const size_t arow0 = (size_t)(m0 + rs0) * lda;
  const size_t arow1 = (size_t)(m0 + rs0 + 16) * lda;
  const size_t brow0 = (size_t)(n0 + rs0) * ldb;
  const size_t brow1 = (size_t)(n0 + rs0 + 16) * ldb;
  bf16* lA0 = &As[(w * 2 + 0) * 512];
  bf16* lA1 = &As[(w * 2 + 1) * 512];
  bf16* lB0 = &Bs[(w * 2 + 0) * 512];
  bf16* lB1 = &Bs[(w * 2 + 1) * 512];

  for (int k0 = 0; k0 < Kdim; k0 += 32) {
    __syncthreads();
    gload16(A + arow0 + k0 + ce, lA0);
    gload16(A + arow1 + k0 + ce, lA1);
    gload16(BT + brow0 + k0 + ce, lB0);
    gload16(BT + brow1 + k0 + ce, lB1);
    __syncthreads();
    bf16x8 af[4], bfr[4];
#pragma unroll
    for (int m = 0; m < 4; ++m)
      af[m] = *(const bf16x8*)&As[(wr * 64 + m * 16 + lr) * 32 + fo];
#pragma unroll
    for (int n = 0; n < 4; ++n)
      bfr[n] = *(const bf16x8*)&Bs[(wc * 64 + n * 16 + lr) * 32 + fo];
#pragma unroll
    for (int m = 0; m < 4; ++m)
#pragma unroll
      for (int n = 0; n < 4; ++n)
        acc[m][n] = __builtin_amdgcn_mfma_f32_16x16x32_bf16(af[m], bfr[n], acc[m][n], 0, 0, 0);
  }

#pragma unroll
  for (int m = 0; m < 4; ++m)
#pragma unroll
    for (int n = 0; n < 4; ++n) {
      int col = n0 + wc * 64 + n * 16 + lr;
      if (MASK && col >= Nvalid) continue;
      size_t rbase = (size_t)(m0 + wr * 64 + m * 16 + lg * 4);
#pragma unroll
      for (int reg = 0; reg < 4; ++reg)
        from_f(C[(rbase + reg) * ldc + col], acc[m][n][reg]);
    }
}

// ---------------- cast fp32 -> bf16 (4/thread) ----------------
__global__ __launch_bounds__(256) void cast_bf16_kernel(
    const float* __restrict__ x, bf16* __restrict__ y) {
  size_t i = ((size_t)blockIdx.x * 256 + threadIdx.x) * 4;
  float4 v = *(const float4*)(x + i);
  y[i + 0] = __float2bfloat16(v.x);
  y[i + 1] = __float2bfloat16(v.y);
  y[i + 2] = __float2bfloat16(v.z);
  y[i + 3] = __float2bfloat16(v.w);
}

// ---------------- transpose + cast: WT[Npad][K] = W[K][N]^T ----------------
__global__ __launch_bounds__(256) void transpose_cast_kernel(
    const float* __restrict__ W, bf16* __restrict__ WT, int N, int K) {
  __shared__ float t[32][33];
  int n0 = blockIdx.x * 32, k0 = blockIdx.y * 32;
  int tx = threadIdx.x & 31, ty = threadIdx.x >> 5;
#pragma unroll
  for (int i = 0; i < 4; ++i) {
    int n = n0 + tx;
    t[ty + i * 8][tx] = (n < N) ? W[(size_t)(k0 + ty + i * 8) * N + n] : 0.f;
  }
  __syncthreads();
#pragma unroll
  for (int i = 0; i < 4; ++i) {
    int nn = ty + i * 8;
    WT[(size_t)(n0 + nn) * K + k0 + tx] = __float2bfloat16(t[tx][nn]);
  }
}

// ---------------- depthwise causal conv1d (K=4) + SiLU ----------------
__global__ __launch_bounds__(256) void conv_silu_kernel(
    const bf16* __restrict__ zx, const float* __restrict__ cw,
    const float* __restrict__ cb, bf16* __restrict__ xc) {
  int idx = blockIdx.x * 256 + threadIdx.x;
  int d = idx & (DINNER - 1);
  int m = idx >> 12;
  int l = m & (SEQLEN - 1);
  int b = m >> 12;
  float acc = cb[d];
#pragma unroll
  for (int k = 0; k < 4; ++k) {
    int li = l - 3 + k;
    if (li >= 0)
      acc += to_f(zx[(size_t)(b * SEQLEN + li) * DPROJ + DINNER + d]) * cw[k * DINNER + d];
  }
  from_f(xc[(size_t)m * DINNER + d], siluf(acc));
}

// ---------------- B/C elu+1 (bf16 out), log-decay la (f32) ----------------
__global__ __launch_bounds__(256) void prep_kernel(
    const bf16* __restrict__ zx, const float* __restrict__ A_log,
    const float* __restrict__ dt_bias, bf16* __restrict__ Bmb,
    bf16* __restrict__ Cmb, float* __restrict__ la) {
  int idx = blockIdx.x * 256 + threadIdx.x;  // m*64 + j
  int j = idx & 63;
  int m = idx >> 6;
  const bf16* row = zx + (size_t)m * DPROJ;
  float bv = to_f(row[2 * DINNER + j]);
  float cv = to_f(row[2 * DINNER + DSTATE + j]);
  float dtl = to_f(row[2 * DINNER + 2 * DSTATE + j]) + dt_bias[j];
  from_f(Bmb[idx], bv > 0.f ? bv + 1.f : expf(bv));
  from_f(Cmb[idx], cv > 0.f ? cv + 1.f : expf(cv));
  float dt = dtl > 20.f ? dtl : log1pf(expf(dtl));
  la[idx] = -dt * expf(A_log[j]);   // log(a)
}

// ---------------- per-chunk inclusive cumsum of log-decay ----------------
__global__ __launch_bounds__(64) void cumsum_kernel(
    const float* __restrict__ la, float* __restrict__ cs) {
  int bid = blockIdx.x;           // b*4096 + h*64 + c
  int c = bid & 63, h = (bid >> 6) & 63, b = bid >> 12;
  int s = threadIdx.x;
  __shared__ float lds[64];
  size_t base = (size_t)(b * SEQLEN + c * CHUNK + s) * 64 + h;
  lds[s] = la[base];
  __syncthreads();
  float acc = 0.f;
  for (int t = 0; t <= s; ++t) acc += lds[t];
  cs[base] = acc;
}

// ---------------- per-chunk state via MFMA: stT[p][n] = sum_s v[s][p]*ksc[s][n] ----------------
__global__ __launch_bounds__(256) void states_mfma(
    const bf16* __restrict__ Bmb, const bf16* __restrict__ xc,
    const float* __restrict__ cs, bf16* __restrict__ st) {
  int bid = blockIdx.x;           // b*4096 + h*64 + c
  int c = bid & 63, h = (bid >> 6) & 63, b = bid >> 12;
  int m0 = b * SEQLEN + c * CHUNK;
  int tid = threadIdx.x, lane = tid & 63, w = tid >> 6;
  int lr = lane & 15, lg = lane >> 4;
  __shared__ bf16 vT[64 * 72];    // [p][s]
  __shared__ bf16 kT[64 * 72];    // [n][s]
  int s4 = tid >> 2, c16 = (tid & 3) * 16;
  float cstot = cs[(size_t)(m0 + 63) * 64 + h];
  float ws = expf(cstot - cs[(size_t)(m0 + s4) * 64 + h]);
  {
    union { bf16x8 v[2]; bf16 hh[16]; } u;
    const bf16x8* pv = (const bf16x8*)&xc[(size_t)(m0 + s4) * DINNER + h * 64 + c16];
    u.v[0] = pv[0]; u.v[1] = pv[1];
#pragma unroll
    for (int i = 0; i < 16; ++i) vT[(c16 + i) * 72 + s4] = u.hh[i];
    const bf16x8* pk = (const bf16x8*)&Bmb[(size_t)(m0 + s4) * 64 + c16];
    u.v[0] = pk[0]; u.v[1] = pk[1];
#pragma unroll
    for (int i = 0; i < 16; ++i) kT[(c16 + i) * 72 + s4] = __float2bfloat16(to_f(u.hh[i]) * ws);
  }
  __syncthreads();
  f32x4 acc[4];
#pragma unroll
  for (int ct = 0; ct < 4; ++ct) acc[ct] = (f32x4){0.f, 0.f, 0.f, 0.f};
#pragma unroll
  for (int ks = 0; ks < 2; ++ks) {
    bf16x8 af = *(const bf16x8*)&vT[(w * 16 + lr) * 72 + ks * 32 + lg * 8];
#pragma unroll
    for (int ct = 0; ct < 4; ++ct) {
      bf16x8 bf_ = *(const bf16x8*)&kT[(ct * 16 + lr) * 72 + ks * 32 + lg * 8];
      acc[ct] = __builtin_amdgcn_mfma_f32_16x16x32_bf16(af, bf_, acc[ct], 0, 0, 0);
    }
  }
  size_t ob = (((size_t)(b * NHEADS + h)) * NCHUNK + c) * 4096;
#pragma unroll
  for (int ct = 0; ct < 4; ++ct) {
    int n = ct * 16 + lr;
#pragma unroll
    for (int r = 0; r < 4; ++r) {
      int p = w * 16 + lg * 4 + r;
      from_f(st[ob + (size_t)p * 64 + n], acc[ct][r]);
    }
  }
}

// ---------------- sequential scan over chunks (in place; stT layout elementwise) ----------------
__global__ __launch_bounds__(256) void scan_kernel(
    const float* __restrict__ cs, bf16* __restrict__ st) {
  int bid = blockIdx.x;           // (b*64+h)*4 + quarter
  int bh = bid >> 2, qq = bid & 3;
  int b = bh >> 6, h = bh & 63;
  int e0 = qq * 1024 + threadIdx.x * 4;
  float hr[4] = {0.f, 0.f, 0.f, 0.f};
  size_t base = (size_t)bh * NCHUNK * 4096;
  typedef __attribute__((ext_vector_type(4))) short bf16x4;
  for (int c = 0; c < NCHUNK; ++c) {
    float d = expf(cs[(size_t)(b * SEQLEN + c * CHUNK + 63) * 64 + h]);
    bf16* p = st + base + (size_t)c * 4096 + e0;
    union { bf16x4 v; bf16 hh[4]; } in, out;
    in.v = *(bf16x4*)p;
#pragma unroll
    for (int i = 0; i < 4; ++i) {
      float sv = to_f(in.hh[i]);
      from_f(out.hh[i], hr[i]);        // emit state at chunk start
      hr[i] = d * hr[i] + sv;
    }
    *(bf16x4*)p = out.v;
  }
}

// ---------------- per-chunk output via MFMA ----------------
// GEMM1: att = q@k^T (masked+decayed) ; GEMM2 (K=128): y = [att | q*e^cs] @ [v ; h_prev] + D*v
__global__ __launch_bounds__(256) void chunk_out_mfma(
    const bf16* __restrict__ Bmb, const bf16* __restrict__ Cmb,
    const bf16* __restrict__ xc, const float* __restrict__ cs,
    const bf16* __restrict__ st, const float* __restrict__ Dp,
    bf16* __restrict__ zx) {
  int bid = blockIdx.x;           // b*4096 + h*64 + c
  int c = bid & 63, h = (bid >> 6) & 63, b = bid >> 12;
  int m0 = b * SEQLEN + c * CHUNK;
  int tid = threadIdx.x, lane = tid & 63, w = tid >> 6;
  int lr = lane & 15, lg = lane >> 4;
  __shared__ bf16 qL[64 * 72];    // q[s][n]; reused for y staging
  __shared__ bf16 kL[64 * 72];    // k[t][n]
  __shared__ bf16 A2[64 * 136];   // [att | qsc]  (A of GEMM2)
  __shared__ bf16 B2[64 * 136];   // [p][t | 64+n] = [v^T | h^T] (BT of GEMM2)
  __shared__ float csl[64];
  int s4 = tid >> 2, c16 = (tid & 3) * 16;

  if (tid < 64) csl[tid] = cs[(size_t)(m0 + tid) * 64 + h];
  {
    const bf16x8* pq = (const bf16x8*)&Cmb[(size_t)(m0 + s4) * 64 + c16];
    *(bf16x8*)&qL[s4 * 72 + c16] = pq[0];
    *(bf16x8*)&qL[s4 * 72 + c16 + 8] = pq[1];
    const bf16x8* pk = (const bf16x8*)&Bmb[(size_t)(m0 + s4) * 64 + c16];
    *(bf16x8*)&kL[s4 * 72 + c16] = pk[0];
    *(bf16x8*)&kL[s4 * 72 + c16 + 8] = pk[1];
  }
  {
    // B2 v part: B2[p][t] = v[t][p]; here t = s4
    union { bf16x8 v[2]; bf16 hh[16]; } u;
    const bf16x8* pv = (const bf16x8*)&xc[(size_t)(m0 + s4) * DINNER + h * 64 + c16];
    u.v[0] = pv[0]; u.v[1] = pv[1];
#pragma unroll
    for (int i = 0; i < 16; ++i) B2[(c16 + i) * 136 + s4] = u.hh[i];
  }
  {
    // B2 h part: B2[p][64+n] = stT[p][n] (direct row copy), p = s4
    size_t hb = (((size_t)(b * NHEADS + h)) * NCHUNK + c) * 4096;
    const bf16x8* ph = (const bf16x8*)&st[hb + (size_t)s4 * 64 + c16];
    *(bf16x8*)&B2[s4 * 136 + 64 + c16] = ph[0];
    *(bf16x8*)&B2[s4 * 136 + 64 + c16 + 8] = ph[1];
  }
  __syncthreads();

  // GEMM1: att rows [w*16, w*16+16)
  f32x4 acc1[4];
#pragma unroll
  for (int ct = 0; ct < 4; ++ct) acc1[ct] = (f32x4){0.f, 0.f, 0.f, 0.f};
#pragma unroll
  for (int ks = 0; ks < 2; ++ks) {
    bf16x8 af = *(const bf16x8*)&qL[(w * 16 + lr) * 72 + ks * 32 + lg * 8];
#pragma unroll
    for (int ct = 0; ct < 4; ++ct) {
      bf16x8 bf_ = *(const bf16x8*)&kL[(ct * 16 + lr) * 72 + ks * 32 + lg * 8];
      acc1[ct] = __builtin_amdgcn_mfma_f32_16x16x32_bf16(af, bf_, acc1[ct], 0, 0, 0);
    }
  }
  // A2 qsc half: A2[s][64+n] = q[s][n] * e^{cs_s}
  {
    float es = expf(csl[s4]);
    union { bf16x8 v[2]; bf16 hh[16]; } u;
    const bf16x8* pq = (const bf16x8*)&qL[s4 * 72 + c16];
    u.v[0] = pq[0]; u.v[1] = pq[1];
#pragma unroll
    for (int i = 0; i < 16; ++i) u.hh[i] = __float2bfloat16(to_f(u.hh[i]) * es);
    *(bf16x8*)&A2[s4 * 136 + 64 + c16] = u.v[0];
    *(bf16x8*)&A2[s4 * 136 + 64 + c16 + 8] = u.v[1];
  }
  // A2 att half with causal mask + decay
#pragma unroll
  for (int ct = 0; ct < 4; ++ct) {
    int t = ct * 16 + lr;
#pragma unroll
    for (int r = 0; r < 4; ++r) {
      int s = w * 16 + lg * 4 + r;
      float val = (t <= s) ? acc1[ct][r] * expf(csl[s] - csl[t]) : 0.f;
      A2[s * 136 + t] = __float2bfloat16(val);
    }
  }
  __syncthreads();

  // GEMM2: y = A2 @ B2^T (K=128), seeded with D*v
  float Dh = Dp[h];
  f32x4 acc2[4];
#pragma unroll
  for (int ct = 0; ct < 4; ++ct) {
    int p = ct * 16 + lr;
#pragma unroll
    for (int r = 0; r < 4; ++r)
      acc2[ct][r] = Dh * to_f(B2[p * 136 + (w * 16 + lg * 4 + r)]);
  }
#pragma unroll
  for (int ks = 0; ks < 4; ++ks) {
    bf16x8 af = *(const bf16x8*)&A2[(w * 16 + lr) * 136 + ks * 32 + lg * 8];
#pragma unroll
    for (int ct = 0; ct < 4; ++ct) {
      bf16x8 bf_ = *(const bf16x8*)&B2[(ct * 16 + lr) * 136 + ks * 32 + lg * 8];
      acc2[ct] = __builtin_amdgcn_mfma_f32_16x16x32_bf16(af, bf_, acc2[ct], 0, 0, 0);
    }
  }
  __syncthreads();
  // stage y into qL [64][72] for vectorized global store
#pragma unroll
  for (int ct = 0; ct < 4; ++ct) {
    int p = ct * 16 + lr;
#pragma unroll
    for (int r = 0; r < 4; ++r)
      qL[(w * 16 + lg * 4 + r) * 72 + p] = __float2bfloat16(acc2[ct][r]);
  }
  __syncthreads();
  {
    const bf16x8* py = (const bf16x8*)&qL[s4 * 72 + c16];
    bf16x8* pg = (bf16x8*)&zx[(size_t)(m0 + s4) * DPROJ + DINNER + h * 64 + c16];
    pg[0] = py[0]; pg[1] = py[1];
  }
}

// ---------------- RMSNorm over 4096 + silu(z) gate ----------------
__global__ __launch_bounds__(256) void rmsnorm_gate_kernel(
    bf16* __restrict__ zx, const float* __restrict__ scale) {
  int m = blockIdx.x;
  int tid = threadIdx.x;
  bf16* row = zx + (size_t)m * DPROJ;   // z at [0,4096), y at [4096,8192)
  float vals[16];
  float ss = 0.f;
#pragma unroll
  for (int i = 0; i < 16; ++i) {
    int d = tid + 256 * i;
    float y = to_f(row[DINNER + d]);
    vals[i] = y;
    ss += y * y;
  }
#pragma unroll
  for (int off = 32; off > 0; off >>= 1) ss += __shfl_down(ss, off, 64);
  __shared__ float red[4];
  if ((tid & 63) == 0) red[tid >> 6] = ss;
  __syncthreads();
  float tot = red[0] + red[1] + red[2] + red[3];
  float inv = rsqrtf(tot / (float)DINNER + RMS_EPS);
#pragma unroll
  for (int i = 0; i < 16; ++i) {
    int d = tid + 256 * i;
    float z = to_f(row[d]);
    from_f(row[DINNER + d], vals[i] * inv * scale[d] * siluf(z));
  }
}

// ---------------- launch ----------------
extern "C" void kernel_launch(void* const* d_in, const int* in_sizes, int n_in,
                              void* d_out, int out_size, void* d_ws, size_t ws_size,
                              hipStream_t stream) {
  const float* u       = (const float*)d_in[0];
  const float* Win     = (const float*)d_in[1];
  const float* cw      = (const float*)d_in[2];
  const float* cb      = (const float*)d_in[3];
  const float* A_log   = (const float*)d_in[4];
  const float* dt_bias = (const float*)d_in[5];
  const float* Dp      = (const float*)d_in[6];
  const float* nscale  = (const float*)d_in[7];
  const float* Wout    = (const float*)d_in[8];
  float* out = (float*)d_out;

  // workspace (~245 MB): zx 137.4MB | xc 67.1MB (ub overlays) | wT 34.6MB | small ~6MB
  bf16* zx = (bf16*)d_ws;
  bf16* xc = zx + (size_t)MTOK * DPROJ;
  bf16* ub = xc;                                  // overlay: ub dead before xc written
  bf16* wT = xc + (size_t)MTOK * DINNER;
  bf16* Bmb = wT + (size_t)DPROJ_PAD * DMODEL;    // MTOK*64 bf16
  bf16* Cmb = Bmb + (size_t)MTOK * 64;
  float* la = (float*)(Cmb + (size_t)MTOK * 64);  // MTOK*64 f32
  float* cs = la + (size_t)MTOK * 64;
  bf16* st = (bf16*)d_out;                        // chunk states stT[p][n], 64 MiB

  // 0a) u -> bf16
  cast_bf16_kernel<<<(MTOK * DMODEL) / (256 * 4), 256, 0, stream>>>(u, ub);
  // 0b) Win^T (padded to 8448 rows) -> bf16
  transpose_cast_kernel<<<dim3(DPROJ_PAD / 32, DMODEL / 32), 256, 0, stream>>>(Win, wT, DPROJ, DMODEL);
  // 1) in-projection: zx = ub @ WinT^T
  gemm_mfma<bf16, true><<<dim3(DPROJ_PAD / 128, MTOK / 128), 256, 0, stream>>>(
      ub, DMODEL, wT, DMODEL, zx, DPROJ, DMODEL, DPROJ);
  // 0c) Wout^T -> bf16 (reuses wT)
  transpose_cast_kernel<<<dim3(DMODEL / 32, DINNER / 32), 256, 0, stream>>>(Wout, wT, DMODEL, DINNER);
  // 2) causal depthwise conv + SiLU -> xc
  conv_silu_kernel<<<(MTOK * DINNER) / 256, 256, 0, stream>>>(zx, cw, cb, xc);
  // 3) B/C elu+1 (bf16), log-decay
  prep_kernel<<<(MTOK * 64) / 256, 256, 0, stream>>>(zx, A_log, dt_bias, Bmb, Cmb, la);
  // 4) per-chunk cumsum
  cumsum_kernel<<<BATCH * NHEADS * NCHUNK, 64, 0, stream>>>(la, cs);
  // 5) per-chunk states (MFMA, transposed output)
  states_mfma<<<BATCH * NHEADS * NCHUNK, 256, 0, stream>>>(Bmb, xc, cs, st);
  // 6) inter-chunk scan (elementwise, 4-way split per (b,h))
  scan_kernel<<<BATCH * NHEADS * 4, 256, 0, stream>>>(cs, st);
  // 7) per-chunk output (MFMA) -> y into zx x-region
  chunk_out_mfma<<<BATCH * NHEADS * NCHUNK, 256, 0, stream>>>(Bmb, Cmb, xc, cs, st, Dp, zx);
  // 8) RMSNorm + silu(z) gate
  rmsnorm_gate_kernel<<<MTOK, 256, 0, stream>>>(zx, nscale);
  // 9) out-projection: out = y @ WoutT^T
  gemm_mfma<float, false><<<dim3(DMODEL / 128, MTOK / 128), 256, 0, stream>>>(
      zx + DINNER, DPROJ, wT, DINNER, out, DMODEL, DINNER, DMODEL);
}